// Round 2
// baseline (328.104 us; speedup 1.0000x reference)
//
#include <hip/hip_runtime.h>
#include <hip/hip_bf16.h>

typedef __bf16 bf16_t;
typedef __bf16 bf16x8 __attribute__((ext_vector_type(8)));
typedef float f32x4 __attribute__((ext_vector_type(4)));

#define M_TOK 128
#define K_IN 4096
#define N_OUT 11008
#define R_LORA 16
#define SCALING 2.0f
#define NTILE 688  // N_OUT / 16; 688 = 8 * 86 -> exact XCD chunking

// ---------------------------------------------------------------------------
// Kernel A: x (fp32) -> xf (bf16, MFMA-A-fragment-contiguous layout) in ws,
// and T = (x @ lora_A^T) * SCALING in ws.
// xf layout: slot(mt, ks, lane) holds 8 bf16, where
//   mt = m>>4 (m-tile), ks = k>>5 (global 32-wide k-step),
//   lane = ((k>>3)&3)*16 + (m&15), j = k&7.
// So in k_main, A-frag for (mt, ks) is ONE contiguous 1 KB read (16 B/lane).
// ---------------------------------------------------------------------------
__global__ __launch_bounds__(256) void k_prep(const float* __restrict__ x,
                                              const float* __restrict__ loraA,
                                              float* __restrict__ T,
                                              bf16_t* __restrict__ xf) {
  const int m = blockIdx.x;
  const int mt = m >> 4;
  const int ml = m & 15;
  __shared__ float xs[K_IN];
  const float4* xr = (const float4*)(x + (size_t)m * K_IN);
#pragma unroll
  for (int c0 = 0; c0 < 2; ++c0) {
    const int c = c0 * 256 + threadIdx.x;  // c = k>>3, 0..511
    float4 vA = xr[2 * c], vB = xr[2 * c + 1];
    ((float4*)xs)[2 * c] = vA;
    ((float4*)xs)[2 * c + 1] = vB;
    bf16x8 pv = {(bf16_t)vA.x, (bf16_t)vA.y, (bf16_t)vA.z, (bf16_t)vA.w,
                 (bf16_t)vB.x, (bf16_t)vB.y, (bf16_t)vB.z, (bf16_t)vB.w};
    const int ks = c >> 2;
    const int lq = (c & 3) * 16 + ml;
    *(bf16x8*)(xf + ((size_t)(mt * 128 + ks) * 64 + lq) * 8) = pv;
  }
  __syncthreads();
  const int w = threadIdx.x >> 6;
  const int lane = threadIdx.x & 63;
  float a0 = 0.f, a1 = 0.f, a2 = 0.f, a3 = 0.f;
  const float4* A0 = (const float4*)(loraA + (size_t)(w * 4 + 0) * K_IN);
  const float4* A1 = (const float4*)(loraA + (size_t)(w * 4 + 1) * K_IN);
  const float4* A2 = (const float4*)(loraA + (size_t)(w * 4 + 2) * K_IN);
  const float4* A3 = (const float4*)(loraA + (size_t)(w * 4 + 3) * K_IN);
  for (int i = lane; i < K_IN / 4; i += 64) {
    float4 xv = ((float4*)xs)[i];
    float4 v0 = A0[i], v1 = A1[i], v2 = A2[i], v3 = A3[i];
    a0 += xv.x * v0.x + xv.y * v0.y + xv.z * v0.z + xv.w * v0.w;
    a1 += xv.x * v1.x + xv.y * v1.y + xv.z * v1.z + xv.w * v1.w;
    a2 += xv.x * v2.x + xv.y * v2.y + xv.z * v2.z + xv.w * v2.w;
    a3 += xv.x * v3.x + xv.y * v3.y + xv.z * v3.z + xv.w * v3.w;
  }
#pragma unroll
  for (int off = 32; off; off >>= 1) {
    a0 += __shfl_down(a0, off);
    a1 += __shfl_down(a1, off);
    a2 += __shfl_down(a2, off);
    a3 += __shfl_down(a3, off);
  }
  if (lane == 0) {
    float* tm = T + m * R_LORA + w * 4;
    tm[0] = a0 * SCALING;
    tm[1] = a1 * SCALING;
    tm[2] = a2 * SCALING;
    tm[3] = a3 * SCALING;
  }
}

// ---------------------------------------------------------------------------
// Kernel B: barrier-free dequant GEMM + fused LoRA epilogue.
// One block = one 16-col tile, full K. 4 waves split K (1024 each).
// Software pipeline: BOTH the qw (HBM) stream and the A-fragment (L2 xf)
// stream are double-buffered in registers, 2 steps deep. Per step:
// consume (counted vmcnt, never drains) -> MFMA -> issue next batches into
// the freed buffers. sched_barrier(0) pins issues within their step.
// LDS used only for the final 4-way cross-wave reduction. No atomics.
// ---------------------------------------------------------------------------
__global__ __launch_bounds__(256, 3) void k_main(const int* __restrict__ qw,
                                                 const int* __restrict__ zr,
                                                 const float* __restrict__ sc,
                                                 const bf16_t* __restrict__ xf,
                                                 const float* __restrict__ T,
                                                 const float* __restrict__ loraB,
                                                 float* __restrict__ out) {
  const int nt = (blockIdx.x & 7) * 86 + (blockIdx.x >> 3);
  const int o0 = nt * 16;
  const int tid = threadIdx.x;
  const int w = tid >> 6;       // k-chunk 0..3
  const int lane = tid & 63;
  const int ol = lane & 15;     // output col within tile (B-frag n)
  const int ocol = o0 + ol;
  const int krow = (lane >> 4) * 8;  // k-slot base within 32-wide step
  const int k0 = w * 1024;

  __shared__ float red[4][M_TOK * 16];  // 32 KB partial sums
  __shared__ float lb[256];             // loraB tile: rows o0..o0+15

  lb[tid] = loraB[(size_t)o0 * R_LORA + tid];

  // hoist dequant params for this column over the wave's 8 k-groups
  float sf[8], nzs[8];
  {
    const int g0 = k0 >> 7;
#pragma unroll
    for (int g = 0; g < 8; ++g) {
      float s_ = sc[(size_t)(g0 + g) * N_OUT + ocol];
      int z_ = zr[(size_t)(g0 + g) * N_OUT + ocol];
      sf[g] = s_;
      nzs[g] = -(float)z_ * s_;
    }
  }

  const int* qp = qw + (size_t)(k0 + krow) * N_OUT + ocol;
  const bf16_t* ap = xf + ((size_t)(k0 >> 5) * 64 + lane) * 8;

  // -------- pipeline preamble: a(0), q(0), a(1), q(1) --------
  bf16x8 aA[8], aB[8];
  int qA[8], qB[8];
#pragma unroll
  for (int mt = 0; mt < 8; ++mt)
    aA[mt] = *(const bf16x8*)(ap + ((size_t)mt * 128 + 0) * 512);
#pragma unroll
  for (int j = 0; j < 8; ++j) qA[j] = qp[(size_t)j * N_OUT];
#pragma unroll
  for (int mt = 0; mt < 8; ++mt)
    aB[mt] = *(const bf16x8*)(ap + ((size_t)mt * 128 + 1) * 512);
  {
    const int* qn = qp + (size_t)32 * N_OUT;
#pragma unroll
    for (int j = 0; j < 8; ++j) qB[j] = qn[(size_t)j * N_OUT];
  }

  f32x4 acc[8];
#pragma unroll
  for (int mt = 0; mt < 8; ++mt) acc[mt] = (f32x4){0.f, 0.f, 0.f, 0.f};

  for (int kk = 0; kk < 32; kk += 2) {
    const int g = kk >> 2;  // same group for kk and kk+1 (even kk)
    // ---- step kk: consume A-buffers, then refill for kk+2 ----
    {
      bf16x8 bf;
#pragma unroll
      for (int j = 0; j < 8; ++j) bf[j] = (bf16_t)fmaf((float)qA[j], sf[g], nzs[g]);
#pragma unroll
      for (int mt = 0; mt < 8; ++mt)
        acc[mt] = __builtin_amdgcn_mfma_f32_16x16x32_bf16(aA[mt], bf, acc[mt], 0, 0, 0);
      if (kk < 30) {
#pragma unroll
        for (int mt = 0; mt < 8; ++mt)
          aA[mt] = *(const bf16x8*)(ap + ((size_t)mt * 128 + kk + 2) * 512);
        const int* qn = qp + (size_t)(kk + 2) * 32 * N_OUT;
#pragma unroll
        for (int j = 0; j < 8; ++j) qA[j] = qn[(size_t)j * N_OUT];
      }
    }
    __builtin_amdgcn_sched_barrier(0);
    // ---- step kk+1: consume B-buffers, then refill for kk+3 ----
    {
      bf16x8 bf;
#pragma unroll
      for (int j = 0; j < 8; ++j) bf[j] = (bf16_t)fmaf((float)qB[j], sf[g], nzs[g]);
#pragma unroll
      for (int mt = 0; mt < 8; ++mt)
        acc[mt] = __builtin_amdgcn_mfma_f32_16x16x32_bf16(aB[mt], bf, acc[mt], 0, 0, 0);
      if (kk < 30) {
#pragma unroll
        for (int mt = 0; mt < 8; ++mt)
          aB[mt] = *(const bf16x8*)(ap + ((size_t)mt * 128 + kk + 3) * 512);
        const int* qn = qp + (size_t)(kk + 3) * 32 * N_OUT;
#pragma unroll
        for (int j = 0; j < 8; ++j) qB[j] = qn[(size_t)j * N_OUT];
      }
    }
    __builtin_amdgcn_sched_barrier(0);
  }

  // stage partials: C/D layout col = lane&15, row = (lane>>4)*4 + r
#pragma unroll
  for (int mt = 0; mt < 8; ++mt) {
    const int mbase = mt * 16 + ((lane >> 4) << 2);
#pragma unroll
    for (int r = 0; r < 4; ++r) red[w][(mbase + r) * 16 + ol] = acc[mt][r];
  }
  __syncthreads();

  // epilogue: 256 threads x 8 outputs; sum 4 partials + fused LoRA, one store
  const int m = tid >> 1;
  const int ob = (tid & 1) * 8;
  float tr[16];
  {
    const float4* Tm4 = (const float4*)(T + (size_t)m * R_LORA);
#pragma unroll
    for (int q = 0; q < 4; ++q) {
      float4 tv = Tm4[q];
      tr[q * 4 + 0] = tv.x;
      tr[q * 4 + 1] = tv.y;
      tr[q * 4 + 2] = tv.z;
      tr[q * 4 + 3] = tv.w;
    }
  }
  float res[8];
#pragma unroll
  for (int i = 0; i < 8; ++i) {
    const int e = m * 16 + ob + i;
    float s = red[0][e] + red[1][e] + red[2][e] + red[3][e];
    const float* lr = &lb[(ob + i) * R_LORA];
    float tv = 0.f;
#pragma unroll
    for (int r = 0; r < 16; ++r) tv = fmaf(tr[r], lr[r], tv);
    res[i] = s + tv;
  }
  float4* op = (float4*)(out + (size_t)m * N_OUT + o0 + ob);
  op[0] = (float4){res[0], res[1], res[2], res[3]};
  op[1] = (float4){res[4], res[5], res[6], res[7]};
}

// ---------------------------------------------------------------------------
extern "C" void kernel_launch(void* const* d_in, const int* in_sizes, int n_in,
                              void* d_out, int out_size, void* d_ws, size_t ws_size,
                              hipStream_t stream) {
  const float* x = (const float*)d_in[0];
  const int* qw = (const int*)d_in[1];
  const int* zr = (const int*)d_in[2];
  const float* sc = (const float*)d_in[3];
  const float* loraA = (const float*)d_in[4];
  const float* loraB = (const float*)d_in[5];
  float* out = (float*)d_out;

  float* T = (float*)d_ws;                     // 128*16 fp32 = 8 KB
  bf16_t* xf = (bf16_t*)((char*)d_ws + 8192);  // 128*4096 bf16 = 1 MB (frag layout)

  k_prep<<<dim3(M_TOK), dim3(256), 0, stream>>>(x, loraA, T, xf);
  k_main<<<dim3(NTILE), dim3(256), 0, stream>>>(qw, zr, sc, xf, T, loraB, out);
}

// Round 3
// 290.658 us; speedup vs baseline: 1.1288x; 1.1288x over previous
//
#include <hip/hip_runtime.h>
#include <hip/hip_bf16.h>

typedef __bf16 bf16_t;
typedef __bf16 bf16x8 __attribute__((ext_vector_type(8)));
typedef float f32x4 __attribute__((ext_vector_type(4)));

#define M_TOK 128
#define K_IN 4096
#define N_OUT 11008
#define R_LORA 16
#define SCALING 2.0f
#define NSTRIPS 172
#define WSTRIDE 72  // bf16 elems per o-row in LDS (144 B, quad-count 9 = odd)

// ---------------------------------------------------------------------------
// Kernel A: x (fp32) -> xf (bf16, MFMA-A-fragment-contiguous layout) in ws,
// and T = (x @ lora_A^T) * SCALING in ws.
// xf layout: slot(mt, ks, lane) holds 8 bf16 where mt=m>>4, ks=k>>5,
//   lane=((k>>3)&3)*16 + (m&15), j=k&7.  In k_main the A-frag for (mt,ks)
//   is ONE contiguous 1 KB wave read (16 B/lane), L2-resident.
// ---------------------------------------------------------------------------
__global__ __launch_bounds__(256) void k_prep(const float* __restrict__ x,
                                              const float* __restrict__ loraA,
                                              float* __restrict__ T,
                                              bf16_t* __restrict__ xf) {
  const int m = blockIdx.x;
  const int mt = m >> 4;
  const int ml = m & 15;
  __shared__ float xs[K_IN];
  const float4* xr = (const float4*)(x + (size_t)m * K_IN);
#pragma unroll
  for (int c0 = 0; c0 < 2; ++c0) {
    const int c = c0 * 256 + threadIdx.x;  // c = k>>3, 0..511
    float4 vA = xr[2 * c], vB = xr[2 * c + 1];
    ((float4*)xs)[2 * c] = vA;
    ((float4*)xs)[2 * c + 1] = vB;
    bf16x8 pv = {(bf16_t)vA.x, (bf16_t)vA.y, (bf16_t)vA.z, (bf16_t)vA.w,
                 (bf16_t)vB.x, (bf16_t)vB.y, (bf16_t)vB.z, (bf16_t)vB.w};
    const int ks = c >> 2;
    const int lq = (c & 3) * 16 + ml;
    *(bf16x8*)(xf + ((size_t)(mt * 128 + ks) * 64 + lq) * 8) = pv;
  }
  __syncthreads();
  const int w = threadIdx.x >> 6;
  const int lane = threadIdx.x & 63;
  float a0 = 0.f, a1 = 0.f, a2 = 0.f, a3 = 0.f;
  const float4* A0 = (const float4*)(loraA + (size_t)(w * 4 + 0) * K_IN);
  const float4* A1 = (const float4*)(loraA + (size_t)(w * 4 + 1) * K_IN);
  const float4* A2 = (const float4*)(loraA + (size_t)(w * 4 + 2) * K_IN);
  const float4* A3 = (const float4*)(loraA + (size_t)(w * 4 + 3) * K_IN);
  for (int i = lane; i < K_IN / 4; i += 64) {
    float4 xv = ((float4*)xs)[i];
    float4 v0 = A0[i], v1 = A1[i], v2 = A2[i], v3 = A3[i];
    a0 += xv.x * v0.x + xv.y * v0.y + xv.z * v0.z + xv.w * v0.w;
    a1 += xv.x * v1.x + xv.y * v1.y + xv.z * v1.z + xv.w * v1.w;
    a2 += xv.x * v2.x + xv.y * v2.y + xv.z * v2.z + xv.w * v2.w;
    a3 += xv.x * v3.x + xv.y * v3.y + xv.z * v3.z + xv.w * v3.w;
  }
#pragma unroll
  for (int off = 32; off; off >>= 1) {
    a0 += __shfl_down(a0, off);
    a1 += __shfl_down(a1, off);
    a2 += __shfl_down(a2, off);
    a3 += __shfl_down(a3, off);
  }
  if (lane == 0) {
    float* tm = T + m * R_LORA + w * 4;
    tm[0] = a0 * SCALING;
    tm[1] = a1 * SCALING;
    tm[2] = a2 * SCALING;
    tm[3] = a3 * SCALING;
  }
}

// ---------------------------------------------------------------------------
// Kernel B: out = T @ lora_B^T (full overwrite of d_out -> handles poison,
// and provides the base the dequant GEMM atomically accumulates onto).
// ---------------------------------------------------------------------------
__global__ __launch_bounds__(256) void k_lora(const float* __restrict__ T,
                                              const float* __restrict__ loraB,
                                              float* __restrict__ out) {
  const int b = blockIdx.x;
  const int m = b / 43;
  const int o = (b % 43) * 256 + threadIdx.x;
  const float* t = T + m * R_LORA;
  const float4* br = (const float4*)(loraB + (size_t)o * R_LORA);
  float4 b0 = br[0], b1 = br[1], b2 = br[2], b3 = br[3];
  float s = t[0] * b0.x + t[1] * b0.y + t[2] * b0.z + t[3] * b0.w +
            t[4] * b1.x + t[5] * b1.y + t[6] * b1.z + t[7] * b1.w +
            t[8] * b2.x + t[9] * b2.y + t[10] * b2.z + t[11] * b2.w +
            t[12] * b3.x + t[13] * b3.y + t[14] * b3.z + t[15] * b3.w;
  out[(size_t)m * N_OUT + o] = s;
}

// ---------------------------------------------------------------------------
// Kernel C: main dequant GEMM. 172 N-strips (64 cols) x 4 K-chunks (1024).
// LDS-staged, double-buffered, BK=64 per barrier step (16 steps).
// NEW vs round-0: 2-step-deep register prefetch of the qw stream (qrA/qrB;
// barriers don't drain vmcnt for register loads), and A-operand read from
// the fragment-contiguous xf (1 coalesced 1 KB wave load per frag, L2-hit).
// Staging: thread (w,lane) owns column lane, rows w*16..w*16+15 of each step.
// LDS [o][k], o-stride 72 bf16 = 144 B (odd quad count -> quads spread).
// ---------------------------------------------------------------------------
__global__ __launch_bounds__(256, 4) void k_main(const int* __restrict__ qw,
                                                 const int* __restrict__ zr,
                                                 const float* __restrict__ sc,
                                                 const bf16_t* __restrict__ xf,
                                                 float* __restrict__ out) {
  const int nb = blockIdx.x % NSTRIPS;
  const int kc = blockIdx.x / NSTRIPS;  // 0..3
  const int o0 = nb * 64;
  const int k0 = kc * 1024;

  __shared__ __align__(16) bf16_t wlds[2][64 * WSTRIDE];  // 18432 B

  const int tid = threadIdx.x;
  const int w = tid >> 6;
  const int lane = tid & 63;
  const int oq = lane;      // staging column within tile
  const int kq = w * 16;    // staging k-base within 64-row step
  const int ocol = o0 + oq;
  const int* qp = qw + (size_t)(k0 + kq) * N_OUT + ocol;

  // hoist all 8 groups' dequant params for this column
  float sf[8], nzs[8];
  {
    const int g0 = k0 >> 7;
#pragma unroll
    for (int g = 0; g < 8; ++g) {
      float s_ = sc[(size_t)(g0 + g) * N_OUT + ocol];
      int z_ = zr[(size_t)(g0 + g) * N_OUT + ocol];
      sf[g] = s_;
      nzs[g] = -(float)z_ * s_;
    }
  }

  // ---- preamble: load q(step0), q(step1); dequant step0 -> lds[0] ----
  int qrA[16], qrB[16];
#pragma unroll
  for (int j = 0; j < 16; ++j) qrA[j] = qp[(size_t)j * N_OUT];
#pragma unroll
  for (int j = 0; j < 16; ++j) qrB[j] = qp[(size_t)(64 + j) * N_OUT];
  {
    bf16x8 wv0, wv1;
#pragma unroll
    for (int j = 0; j < 8; ++j) {
      wv0[j] = (bf16_t)fmaf((float)qrA[j], sf[0], nzs[0]);
      wv1[j] = (bf16_t)fmaf((float)qrA[8 + j], sf[0], nzs[0]);
    }
    *(bf16x8*)&wlds[0][oq * WSTRIDE + kq] = wv0;
    *(bf16x8*)&wlds[0][oq * WSTRIDE + kq + 8] = wv1;
  }

  f32x4 acc[2][4];
#pragma unroll
  for (int mt = 0; mt < 2; ++mt)
#pragma unroll
    for (int ot = 0; ot < 4; ++ot) acc[mt][ot] = (f32x4){0.f, 0.f, 0.f, 0.f};

  // A-operand base: wave w owns m-rows w*32..w*32+31 -> mt tiles {2w, 2w+1}
  const bf16_t* ap = xf + (size_t)lane * 8;
  const int aq = (lane >> 4) * 8;  // B-frag k-offset within 32-wide slice
  const int ol = lane & 15;

#define MFMA_STEP(STEP, BUF)                                                       \
  {                                                                                \
    _Pragma("unroll") for (int ks = 0; ks < 2; ++ks) {                             \
      const int ksg = kc * 32 + (STEP)*2 + ks;                                     \
      bf16x8 a0 = *(const bf16x8*)(ap + ((size_t)((2 * w) * 128 + ksg)) * 512);    \
      bf16x8 a1 = *(const bf16x8*)(ap + ((size_t)((2 * w + 1) * 128 + ksg)) * 512);\
      _Pragma("unroll") for (int ot = 0; ot < 4; ++ot) {                           \
        bf16x8 bfrag = *(bf16x8*)&wlds[BUF][(ot * 16 + ol) * WSTRIDE + ks * 32 + aq];\
        acc[0][ot] = __builtin_amdgcn_mfma_f32_16x16x32_bf16(a0, bfrag, acc[0][ot], 0, 0, 0); \
        acc[1][ot] = __builtin_amdgcn_mfma_f32_16x16x32_bf16(a1, bfrag, acc[1][ot], 0, 0, 0); \
      }                                                                            \
    }                                                                              \
  }

#define DEQ_STORE(QR, G, BUF)                                                      \
  {                                                                                \
    bf16x8 wv0, wv1;                                                               \
    _Pragma("unroll") for (int j = 0; j < 8; ++j) {                                \
      wv0[j] = (bf16_t)fmaf((float)QR[j], sf[G], nzs[G]);                          \
      wv1[j] = (bf16_t)fmaf((float)QR[8 + j], sf[G], nzs[G]);                      \
    }                                                                              \
    *(bf16x8*)&wlds[BUF][oq * WSTRIDE + kq] = wv0;                                 \
    *(bf16x8*)&wlds[BUF][oq * WSTRIDE + kq + 8] = wv1;                             \
  }

#pragma unroll
  for (int s2 = 0; s2 < 8; ++s2) {
    const int step = s2 * 2;
    // ---- even step (buf 0): lds[0]=data(step), qrB=raw(step+1) ----
    __syncthreads();
    if (step + 2 < 16) {
      const int* qn = qp + (size_t)(step + 2) * 64 * N_OUT;
#pragma unroll
      for (int j = 0; j < 16; ++j) qrA[j] = qn[(size_t)j * N_OUT];
    }
    MFMA_STEP(step, 0)
    DEQ_STORE(qrB, (step + 1) >> 1, 1)
    // ---- odd step (buf 1): lds[1]=data(step+1), qrA=raw(step+2) ----
    __syncthreads();
    if (step + 3 < 16) {
      const int* qn = qp + (size_t)(step + 3) * 64 * N_OUT;
#pragma unroll
      for (int j = 0; j < 16; ++j) qrB[j] = qn[(size_t)j * N_OUT];
    }
    MFMA_STEP(step + 1, 1)
    if (step + 2 < 16) DEQ_STORE(qrA, (step + 2) >> 1, 0)
  }

  // epilogue: C/D layout col = lane&15, row = (lane>>4)*4 + r
#pragma unroll
  for (int mt = 0; mt < 2; ++mt) {
    const int m = w * 32 + mt * 16 + ((lane >> 4) << 2);
#pragma unroll
    for (int ot = 0; ot < 4; ++ot) {
      const int o = o0 + ot * 16 + ol;
#pragma unroll
      for (int r = 0; r < 4; ++r)
        unsafeAtomicAdd(&out[(size_t)(m + r) * N_OUT + o], acc[mt][ot][r]);
    }
  }
#undef MFMA_STEP
#undef DEQ_STORE
}

// ---------------------------------------------------------------------------
extern "C" void kernel_launch(void* const* d_in, const int* in_sizes, int n_in,
                              void* d_out, int out_size, void* d_ws, size_t ws_size,
                              hipStream_t stream) {
  const float* x = (const float*)d_in[0];
  const int* qw = (const int*)d_in[1];
  const int* zr = (const int*)d_in[2];
  const float* sc = (const float*)d_in[3];
  const float* loraA = (const float*)d_in[4];
  const float* loraB = (const float*)d_in[5];
  float* out = (float*)d_out;

  float* T = (float*)d_ws;                     // 128*16 fp32 = 8 KB
  bf16_t* xf = (bf16_t*)((char*)d_ws + 8192);  // 128*4096 bf16 = 1 MB (frag layout)

  k_prep<<<dim3(M_TOK), dim3(256), 0, stream>>>(x, loraA, T, xf);
  k_lora<<<dim3(M_TOK * 43), dim3(256), 0, stream>>>(T, loraB, out);
  k_main<<<dim3(NSTRIPS * 4), dim3(256), 0, stream>>>(qw, zr, sc, xf, out);
}